// Round 1
// baseline (1140.686 us; speedup 1.0000x reference)
//
#include <hip/hip_runtime.h>
#include <hip/hip_bf16.h>

#define T_TOK 2048
#define H_DIM 2048
#define I_DIM 2048
#define E_NUM 8
#define TOPK  2

#define BM 128
#define BN 128
#define BK 32
#define LDK 40  // padded k-stride (bf16 elems): 80B row stride -> 20-bank lane stride, 2-way free

typedef float  floatx4 __attribute__((ext_vector_type(4)));
typedef __bf16 bf16x8  __attribute__((ext_vector_type(8)));
typedef __bf16 bf16x4  __attribute__((ext_vector_type(4)));

// ---------------------------------------------------------------------------
// Kernel 1: router — logits, top-2, renormalized weights, per-expert lists
// ---------------------------------------------------------------------------
__global__ __launch_bounds__(64) void router_kernel(
    const float* __restrict__ hs, const float* __restrict__ gate_w,
    int* __restrict__ counts, int* __restrict__ lists, float* __restrict__ wpair)
{
    const int t    = blockIdx.x;
    const int lane = threadIdx.x;

    float acc[E_NUM];
#pragma unroll
    for (int e = 0; e < E_NUM; e++) acc[e] = 0.f;

    const float4* hsrow = (const float4*)(hs + (size_t)t * H_DIM);
#pragma unroll
    for (int it = 0; it < (H_DIM / 4) / 64; it++) {
        const int c = lane + it * 64;
        const float4 x = hsrow[c];
#pragma unroll
        for (int e = 0; e < E_NUM; e++) {
            const float4 w = ((const float4*)(gate_w + (size_t)e * H_DIM))[c];
            acc[e] += x.x * w.x + x.y * w.y + x.z * w.z + x.w * w.w;
        }
    }
#pragma unroll
    for (int e = 0; e < E_NUM; e++) {
        float v = acc[e];
        for (int off = 32; off >= 1; off >>= 1) v += __shfl_xor(v, off, 64);
        acc[e] = v;
    }
    if (lane == 0) {
        float l0 = -1e30f; int i0 = 0;
        for (int e = 0; e < E_NUM; e++) if (acc[e] > l0) { l0 = acc[e]; i0 = e; }
        float l1 = -1e30f; int i1 = (i0 == 0) ? 1 : 0;
        for (int e = 0; e < E_NUM; e++) if (e != i0 && acc[e] > l1) { l1 = acc[e]; i1 = e; }
        // renormalized top-2 softmax == softmax over the two top logits
        const float e1 = __expf(l1 - l0);
        const float s  = 1.f + e1;
        const float w0 = 1.f / s;
        const float w1 = e1 / s;
        const int p0 = atomicAdd(&counts[i0], 1);
        lists[i0 * T_TOK + p0] = 2 * t;
        const int p1 = atomicAdd(&counts[i1], 1);
        lists[i1 * T_TOK + p1] = 2 * t + 1;
        wpair[2 * t]     = w0;
        wpair[2 * t + 1] = w1;
    }
}

// ---------------------------------------------------------------------------
// Kernel 2: fused gate/up GEMM + SiLU.  A = silu(X@W1) * (X@W3), bf16 out.
// X rows gathered via per-expert list (pair slot p -> token p>>1).
// ---------------------------------------------------------------------------
__global__ __launch_bounds__(256, 2) void gemm1_kernel(
    const float* __restrict__ hs, const float* __restrict__ w1,
    const float* __restrict__ w3, const int* __restrict__ counts,
    const int* __restrict__ lists, __bf16* __restrict__ Abuf)
{
    const int e   = blockIdx.z;
    const int n_e = counts[e];
    const int m0  = blockIdx.y * BM;
    if (m0 >= n_e) return;
    const int n0 = blockIdx.x * BN;

    const int*   list = lists + e * T_TOK;
    const float* w1e  = w1 + (size_t)e * H_DIM * I_DIM;
    const float* w3e  = w3 + (size_t)e * H_DIM * I_DIM;

    __shared__ __bf16 Xs[BM][LDK];
    __shared__ __bf16 B1s[BN][LDK];
    __shared__ __bf16 B3s[BN][LDK];

    const int tid  = threadIdx.x;
    const int xrow = tid >> 3;          // 0..31 (+i*32)
    const int xkc  = (tid & 7) * 4;     // k chunk (4 floats)
    const int wrow = tid >> 5;          // 0..7 (+i*8): k within tile
    const int wnc  = (tid & 31) * 4;    // n chunk (4 floats)

    int tok[4];
#pragma unroll
    for (int i = 0; i < 4; i++) {
        const int r = m0 + xrow + i * 32;
        tok[i] = (r < n_e) ? (list[r] >> 1) : 0;   // OOB rows: garbage, discarded at store
    }

    const int wave = tid >> 6;
    const int lane = tid & 63;
    const int wm   = (wave >> 1) * 64;
    const int wn   = (wave & 1) * 64;
    const int lrow = lane & 15;
    const int quad = lane >> 4;

    floatx4 accG[4][4], accU[4][4];
#pragma unroll
    for (int i = 0; i < 4; i++)
#pragma unroll
        for (int j = 0; j < 4; j++) {
            accG[i][j] = (floatx4){0.f, 0.f, 0.f, 0.f};
            accU[i][j] = (floatx4){0.f, 0.f, 0.f, 0.f};
        }

    for (int k0 = 0; k0 < H_DIM; k0 += BK) {
        // stage X tile (gathered rows, fp32 -> bf16)
#pragma unroll
        for (int i = 0; i < 4; i++) {
            const float4 x = *(const float4*)(hs + (size_t)tok[i] * H_DIM + k0 + xkc);
            const bf16x4 v = {(__bf16)x.x, (__bf16)x.y, (__bf16)x.z, (__bf16)x.w};
            *(bf16x4*)&Xs[xrow + i * 32][xkc] = v;
        }
        // stage W1/W3 tiles transposed: Bs[n][k]
#pragma unroll
        for (int i = 0; i < 4; i++) {
            const int k = wrow + i * 8;
            const float4 a = *(const float4*)(w1e + (size_t)(k0 + k) * I_DIM + n0 + wnc);
            B1s[wnc + 0][k] = (__bf16)a.x; B1s[wnc + 1][k] = (__bf16)a.y;
            B1s[wnc + 2][k] = (__bf16)a.z; B1s[wnc + 3][k] = (__bf16)a.w;
            const float4 b = *(const float4*)(w3e + (size_t)(k0 + k) * I_DIM + n0 + wnc);
            B3s[wnc + 0][k] = (__bf16)b.x; B3s[wnc + 1][k] = (__bf16)b.y;
            B3s[wnc + 2][k] = (__bf16)b.z; B3s[wnc + 3][k] = (__bf16)b.w;
        }
        __syncthreads();

        bf16x8 af[4], b1f[4], b3f[4];
#pragma unroll
        for (int i = 0; i < 4; i++) {
            af[i]  = *(const bf16x8*)&Xs [wm + i * 16 + lrow][quad * 8];
            b1f[i] = *(const bf16x8*)&B1s[wn + i * 16 + lrow][quad * 8];
            b3f[i] = *(const bf16x8*)&B3s[wn + i * 16 + lrow][quad * 8];
        }
#pragma unroll
        for (int i = 0; i < 4; i++)
#pragma unroll
            for (int j = 0; j < 4; j++) {
                accG[i][j] = __builtin_amdgcn_mfma_f32_16x16x32_bf16(af[i], b1f[j], accG[i][j], 0, 0, 0);
                accU[i][j] = __builtin_amdgcn_mfma_f32_16x16x32_bf16(af[i], b3f[j], accU[i][j], 0, 0, 0);
            }
        __syncthreads();
    }

    // epilogue: silu(g)*u -> Abuf[p]  (C/D layout: col=lane&15, row=quad*4+reg)
#pragma unroll
    for (int i = 0; i < 4; i++) {
#pragma unroll
        for (int r = 0; r < 4; r++) {
            const int row = m0 + wm + i * 16 + quad * 4 + r;
            if (row < n_e) {
                const int p = list[row];
                __bf16* dst = Abuf + (size_t)p * I_DIM + n0 + wn + lrow;
#pragma unroll
                for (int j = 0; j < 4; j++) {
                    const float g = accG[i][j][r];
                    const float u = accU[i][j][r];
                    const float s = g / (1.f + __expf(-g));
                    dst[j * 16] = (__bf16)(s * u);
                }
            }
        }
    }
}

// ---------------------------------------------------------------------------
// Kernel 3: down-proj GEMM.  Y[p] = A[p] @ W2[e], bf16 out.
// ---------------------------------------------------------------------------
__global__ __launch_bounds__(256, 2) void gemm2_kernel(
    const __bf16* __restrict__ Abuf, const float* __restrict__ w2,
    const int* __restrict__ counts, const int* __restrict__ lists,
    __bf16* __restrict__ Ybuf)
{
    const int e   = blockIdx.z;
    const int n_e = counts[e];
    const int m0  = blockIdx.y * BM;
    if (m0 >= n_e) return;
    const int n0 = blockIdx.x * BN;

    const int*   list = lists + e * T_TOK;
    const float* w2e  = w2 + (size_t)e * I_DIM * H_DIM;

    __shared__ __bf16 As[BM][LDK];
    __shared__ __bf16 Bs[BN][LDK];

    const int tid  = threadIdx.x;
    const int arow = tid >> 2;          // 0..63 (+i*64)
    const int akc  = (tid & 3) * 8;     // k chunk (8 bf16)
    const int wrow = tid >> 5;
    const int wnc  = (tid & 31) * 4;

    int prow[2];
#pragma unroll
    for (int i = 0; i < 2; i++) {
        const int r = m0 + arow + i * 64;
        prow[i] = (r < n_e) ? list[r] : 0;
    }

    const int wave = tid >> 6;
    const int lane = tid & 63;
    const int wm   = (wave >> 1) * 64;
    const int wn   = (wave & 1) * 64;
    const int lrow = lane & 15;
    const int quad = lane >> 4;

    floatx4 acc[4][4];
#pragma unroll
    for (int i = 0; i < 4; i++)
#pragma unroll
        for (int j = 0; j < 4; j++) acc[i][j] = (floatx4){0.f, 0.f, 0.f, 0.f};

    for (int k0 = 0; k0 < I_DIM; k0 += BK) {
#pragma unroll
        for (int i = 0; i < 2; i++) {
            const bf16x8 v = *(const bf16x8*)(Abuf + (size_t)prow[i] * I_DIM + k0 + akc);
            *(bf16x8*)&As[arow + i * 64][akc] = v;
        }
#pragma unroll
        for (int i = 0; i < 4; i++) {
            const int k = wrow + i * 8;
            const float4 a = *(const float4*)(w2e + (size_t)(k0 + k) * H_DIM + n0 + wnc);
            Bs[wnc + 0][k] = (__bf16)a.x; Bs[wnc + 1][k] = (__bf16)a.y;
            Bs[wnc + 2][k] = (__bf16)a.z; Bs[wnc + 3][k] = (__bf16)a.w;
        }
        __syncthreads();

        bf16x8 af[4], bf[4];
#pragma unroll
        for (int i = 0; i < 4; i++) {
            af[i] = *(const bf16x8*)&As[wm + i * 16 + lrow][quad * 8];
            bf[i] = *(const bf16x8*)&Bs[wn + i * 16 + lrow][quad * 8];
        }
#pragma unroll
        for (int i = 0; i < 4; i++)
#pragma unroll
            for (int j = 0; j < 4; j++)
                acc[i][j] = __builtin_amdgcn_mfma_f32_16x16x32_bf16(af[i], bf[j], acc[i][j], 0, 0, 0);
        __syncthreads();
    }

#pragma unroll
    for (int i = 0; i < 4; i++) {
#pragma unroll
        for (int r = 0; r < 4; r++) {
            const int row = m0 + wm + i * 16 + quad * 4 + r;
            if (row < n_e) {
                const int p = list[row];
                __bf16* dst = Ybuf + (size_t)p * H_DIM + n0 + wn + lrow;
#pragma unroll
                for (int j = 0; j < 4; j++) dst[j * 16] = (__bf16)acc[i][j][r];
            }
        }
    }
}

// ---------------------------------------------------------------------------
// Kernel 4: combine.  out[t] = w[2t]*Y[2t] + w[2t+1]*Y[2t+1]  (fp32 out)
// ---------------------------------------------------------------------------
__global__ __launch_bounds__(256) void combine_kernel(
    const __bf16* __restrict__ Ybuf, const float* __restrict__ wpair,
    float* __restrict__ out)
{
    const int idx = blockIdx.x * 256 + threadIdx.x;   // T*H/4 threads
    const int t   = idx >> 9;                         // 512 4-wide chunks per token
    const int hc  = (idx & 511) * 4;
    const float w0 = wpair[2 * t];
    const float w1 = wpair[2 * t + 1];
    const __bf16* y0 = Ybuf + (size_t)(2 * t) * H_DIM + hc;
    const __bf16* y1 = y0 + H_DIM;
    float4 o;
    o.x = w0 * (float)y0[0] + w1 * (float)y1[0];
    o.y = w0 * (float)y0[1] + w1 * (float)y1[1];
    o.z = w0 * (float)y0[2] + w1 * (float)y1[2];
    o.w = w0 * (float)y0[3] + w1 * (float)y1[3];
    *(float4*)(out + (size_t)t * H_DIM + hc) = o;
}

// ---------------------------------------------------------------------------
extern "C" void kernel_launch(void* const* d_in, const int* in_sizes, int n_in,
                              void* d_out, int out_size, void* d_ws, size_t ws_size,
                              hipStream_t stream)
{
    const float* hs     = (const float*)d_in[0];
    const float* gate_w = (const float*)d_in[1];
    const float* w1     = (const float*)d_in[2];
    const float* w3     = (const float*)d_in[3];
    const float* w2     = (const float*)d_in[4];
    float*       out    = (float*)d_out;

    char* ws = (char*)d_ws;
    int*    counts = (int*)(ws + 0);                                   //    32 B
    float*  wpair  = (float*)(ws + 1024);                              //  16 KB
    int*    lists  = (int*)(ws + 32768);                               //  64 KB
    __bf16* Abuf   = (__bf16*)(ws + (1 << 17));                        // 16.8 MB
    __bf16* Ybuf   = (__bf16*)(ws + (1 << 17) +
                               (size_t)2 * T_TOK * I_DIM * sizeof(__bf16)); // 16.8 MB

    hipMemsetAsync(counts, 0, E_NUM * sizeof(int), stream);

    router_kernel<<<T_TOK, 64, 0, stream>>>(hs, gate_w, counts, lists, wpair);

    gemm1_kernel<<<dim3(I_DIM / BN, T_TOK / BM, E_NUM), 256, 0, stream>>>(
        hs, w1, w3, counts, lists, Abuf);

    gemm2_kernel<<<dim3(H_DIM / BN, T_TOK / BM, E_NUM), 256, 0, stream>>>(
        Abuf, w2, counts, lists, Ybuf);

    combine_kernel<<<(T_TOK * H_DIM / 4) / 256, 256, 0, stream>>>(Ybuf, wpair, out);
}

// Round 2
// 728.726 us; speedup vs baseline: 1.5653x; 1.5653x over previous
//
#include <hip/hip_runtime.h>
#include <hip/hip_bf16.h>

#define T_TOK 2048
#define H_DIM 2048
#define I_DIM 2048
#define E_NUM 8
#define TOPK  2

#define BM 128
#define BN 128
#define BK 64   // 8 granules of 16B (8 bf16) per LDS row

typedef float  floatx4 __attribute__((ext_vector_type(4)));
typedef __bf16 bf16x8  __attribute__((ext_vector_type(8)));
typedef __bf16 bf16x4  __attribute__((ext_vector_type(4)));

// XOR-swizzled LDS granule address (16B granules, 8 per 128-byte row).
// Bank position = g ^ ((row>>1)&7): conflict-free (structural-min) for both
// the staging writes (lane n-stride 4 or 1) and the b128 fragment reads.
__device__ __forceinline__ int swz(int row, int g) {
    return (row * 8 + (g ^ ((row >> 1) & 7))) * 16;
}

// ---------------------------------------------------------------------------
// Kernel 1: router — logits, top-2, renormalized weights, per-expert lists
// ---------------------------------------------------------------------------
__global__ __launch_bounds__(64) void router_kernel(
    const float* __restrict__ hs, const float* __restrict__ gate_w,
    int* __restrict__ counts, int* __restrict__ lists, float* __restrict__ wpair)
{
    const int t    = blockIdx.x;
    const int lane = threadIdx.x;

    float acc[E_NUM];
#pragma unroll
    for (int e = 0; e < E_NUM; e++) acc[e] = 0.f;

    const float4* hsrow = (const float4*)(hs + (size_t)t * H_DIM);
#pragma unroll
    for (int it = 0; it < (H_DIM / 4) / 64; it++) {
        const int c = lane + it * 64;
        const float4 x = hsrow[c];
#pragma unroll
        for (int e = 0; e < E_NUM; e++) {
            const float4 w = ((const float4*)(gate_w + (size_t)e * H_DIM))[c];
            acc[e] += x.x * w.x + x.y * w.y + x.z * w.z + x.w * w.w;
        }
    }
#pragma unroll
    for (int e = 0; e < E_NUM; e++) {
        float v = acc[e];
        for (int off = 32; off >= 1; off >>= 1) v += __shfl_xor(v, off, 64);
        acc[e] = v;
    }
    if (lane == 0) {
        float l0 = -1e30f; int i0 = 0;
        for (int e = 0; e < E_NUM; e++) if (acc[e] > l0) { l0 = acc[e]; i0 = e; }
        float l1 = -1e30f; int i1 = (i0 == 0) ? 1 : 0;
        for (int e = 0; e < E_NUM; e++) if (e != i0 && acc[e] > l1) { l1 = acc[e]; i1 = e; }
        const float e1 = __expf(l1 - l0);
        const float s  = 1.f + e1;
        const int p0 = atomicAdd(&counts[i0], 1);
        lists[i0 * T_TOK + p0] = 2 * t;
        const int p1 = atomicAdd(&counts[i1], 1);
        lists[i1 * T_TOK + p1] = 2 * t + 1;
        wpair[2 * t]     = 1.f / s;
        wpair[2 * t + 1] = e1 / s;
    }
}

// ---------------------------------------------------------------------------
// Kernel 2: fused gate/up GEMM + SiLU.  A = silu(X@W1) * (X@W3), bf16 out.
// ---------------------------------------------------------------------------
__global__ __launch_bounds__(256, 2) void gemm1_kernel(
    const float* __restrict__ hs, const float* __restrict__ w1,
    const float* __restrict__ w3, const int* __restrict__ counts,
    const int* __restrict__ lists, __bf16* __restrict__ Abuf)
{
    const int e   = blockIdx.z;
    const int n_e = counts[e];
    const int m0  = blockIdx.y * BM;
    if (m0 >= n_e) return;
    const int n0 = blockIdx.x * BN;

    const int*   list = lists + e * T_TOK;
    const float* w1e  = w1 + (size_t)e * H_DIM * I_DIM;
    const float* w3e  = w3 + (size_t)e * H_DIM * I_DIM;

    __shared__ __align__(16) __bf16 Xs [BM * BK];
    __shared__ __align__(16) __bf16 B1s[BN * BK];
    __shared__ __align__(16) __bf16 B3s[BN * BK];

    const int tid = threadIdx.x;
    // X staging: thread -> (m = xm+16i, granule xg, half xh)
    const int xm = tid >> 4;
    const int xg = (tid & 15) >> 1;
    const int xh = tid & 1;
    // W staging: thread -> (k-granule kb, n-chunk 4*nc)
    const int kb = tid >> 5;          // 0..7
    const int nc = tid & 31;          // 0..31

    int tok[8];
#pragma unroll
    for (int i = 0; i < 8; i++) {
        const int r = m0 + xm + 16 * i;
        tok[i] = (r < n_e) ? (list[r] >> 1) : 0;
    }

    const int wave = tid >> 6;
    const int lane = tid & 63;
    const int wm   = (wave >> 1) * 64;
    const int wn   = (wave & 1) * 64;
    const int lrow = lane & 15;
    const int quad = lane >> 4;

    floatx4 accG[4][4], accU[4][4];
#pragma unroll
    for (int i = 0; i < 4; i++)
#pragma unroll
        for (int j = 0; j < 4; j++) {
            accG[i][j] = (floatx4){0.f, 0.f, 0.f, 0.f};
            accU[i][j] = (floatx4){0.f, 0.f, 0.f, 0.f};
        }

    for (int k0 = 0; k0 < H_DIM; k0 += BK) {
        // ---- stage X tile (gathered rows, fp32 -> bf16, b64 swizzled writes)
#pragma unroll
        for (int i = 0; i < 8; i++) {
            const int m = xm + 16 * i;
            const float4 x = *(const float4*)(hs + (size_t)tok[i] * H_DIM + k0 + xg * 8 + xh * 4);
            const bf16x4 v = {(__bf16)x.x, (__bf16)x.y, (__bf16)x.z, (__bf16)x.w};
            *(bf16x4*)((char*)Xs + swz(m, xg) + xh * 8) = v;
        }
        // ---- stage W1 tile: 8 coalesced float4 loads, register transpose,
        //      4 b128 swizzled writes (rows n = 4nc+nn, granule kb)
        {
            float4 f[8];
#pragma unroll
            for (int j = 0; j < 8; j++)
                f[j] = *(const float4*)(w1e + (size_t)(k0 + 8 * kb + j) * I_DIM + n0 + 4 * nc);
#pragma unroll
            for (int nn = 0; nn < 4; nn++) {
                bf16x8 w;
#pragma unroll
                for (int j = 0; j < 8; j++) w[j] = (__bf16)((const float*)&f[j])[nn];
                *(bf16x8*)((char*)B1s + swz(4 * nc + nn, kb)) = w;
            }
        }
        // ---- stage W3 tile
        {
            float4 f[8];
#pragma unroll
            for (int j = 0; j < 8; j++)
                f[j] = *(const float4*)(w3e + (size_t)(k0 + 8 * kb + j) * I_DIM + n0 + 4 * nc);
#pragma unroll
            for (int nn = 0; nn < 4; nn++) {
                bf16x8 w;
#pragma unroll
                for (int j = 0; j < 8; j++) w[j] = (__bf16)((const float*)&f[j])[nn];
                *(bf16x8*)((char*)B3s + swz(4 * nc + nn, kb)) = w;
            }
        }
        __syncthreads();

#pragma unroll
        for (int s = 0; s < 2; s++) {
            bf16x8 af[4], b1f[4], b3f[4];
#pragma unroll
            for (int i = 0; i < 4; i++)
                af[i]  = *(const bf16x8*)((char*)Xs  + swz(wm + i * 16 + lrow, 4 * s + quad));
#pragma unroll
            for (int j = 0; j < 4; j++) {
                b1f[j] = *(const bf16x8*)((char*)B1s + swz(wn + j * 16 + lrow, 4 * s + quad));
                b3f[j] = *(const bf16x8*)((char*)B3s + swz(wn + j * 16 + lrow, 4 * s + quad));
            }
#pragma unroll
            for (int i = 0; i < 4; i++)
#pragma unroll
                for (int j = 0; j < 4; j++) {
                    accG[i][j] = __builtin_amdgcn_mfma_f32_16x16x32_bf16(af[i], b1f[j], accG[i][j], 0, 0, 0);
                    accU[i][j] = __builtin_amdgcn_mfma_f32_16x16x32_bf16(af[i], b3f[j], accU[i][j], 0, 0, 0);
                }
        }
        __syncthreads();
    }

    // epilogue: silu(g)*u -> Abuf[p]  (C/D layout: col=lane&15, row=quad*4+reg)
#pragma unroll
    for (int i = 0; i < 4; i++) {
#pragma unroll
        for (int r = 0; r < 4; r++) {
            const int row = m0 + wm + i * 16 + quad * 4 + r;
            if (row < n_e) {
                const int p = list[row];
                __bf16* dst = Abuf + (size_t)p * I_DIM + n0 + wn + lrow;
#pragma unroll
                for (int j = 0; j < 4; j++) {
                    const float g = accG[i][j][r];
                    const float u = accU[i][j][r];
                    const float sv = g / (1.f + __expf(-g));
                    dst[j * 16] = (__bf16)(sv * u);
                }
            }
        }
    }
}

// ---------------------------------------------------------------------------
// Kernel 3: down-proj GEMM.  Y[p] = A[p] @ W2[e], bf16 out.
// ---------------------------------------------------------------------------
__global__ __launch_bounds__(256, 2) void gemm2_kernel(
    const __bf16* __restrict__ Abuf, const float* __restrict__ w2,
    const int* __restrict__ counts, const int* __restrict__ lists,
    __bf16* __restrict__ Ybuf)
{
    const int e   = blockIdx.z;
    const int n_e = counts[e];
    const int m0  = blockIdx.y * BM;
    if (m0 >= n_e) return;
    const int n0 = blockIdx.x * BN;

    const int*   list = lists + e * T_TOK;
    const float* w2e  = w2 + (size_t)e * I_DIM * H_DIM;

    __shared__ __align__(16) __bf16 As[BM * BK];
    __shared__ __align__(16) __bf16 Bs[BN * BK];

    const int tid = threadIdx.x;
    // A staging: thread -> (m = am+32i, granule ag)
    const int am = tid >> 3;          // 0..31
    const int ag = tid & 7;           // 0..7
    // W staging
    const int kb = tid >> 5;
    const int nc = tid & 31;

    int prow[4];
#pragma unroll
    for (int i = 0; i < 4; i++) {
        const int r = m0 + am + 32 * i;
        prow[i] = (r < n_e) ? list[r] : 0;
    }

    const int wave = tid >> 6;
    const int lane = tid & 63;
    const int wm   = (wave >> 1) * 64;
    const int wn   = (wave & 1) * 64;
    const int lrow = lane & 15;
    const int quad = lane >> 4;

    floatx4 acc[4][4];
#pragma unroll
    for (int i = 0; i < 4; i++)
#pragma unroll
        for (int j = 0; j < 4; j++) acc[i][j] = (floatx4){0.f, 0.f, 0.f, 0.f};

    for (int k0 = 0; k0 < I_DIM; k0 += BK) {
        // ---- stage A tile (bf16 gathered rows, b128 swizzled writes)
#pragma unroll
        for (int i = 0; i < 4; i++) {
            const int m = am + 32 * i;
            const bf16x8 v = *(const bf16x8*)(Abuf + (size_t)prow[i] * I_DIM + k0 + 8 * ag);
            *(bf16x8*)((char*)As + swz(m, ag)) = v;
        }
        // ---- stage W2 tile
        {
            float4 f[8];
#pragma unroll
            for (int j = 0; j < 8; j++)
                f[j] = *(const float4*)(w2e + (size_t)(k0 + 8 * kb + j) * H_DIM + n0 + 4 * nc);
#pragma unroll
            for (int nn = 0; nn < 4; nn++) {
                bf16x8 w;
#pragma unroll
                for (int j = 0; j < 8; j++) w[j] = (__bf16)((const float*)&f[j])[nn];
                *(bf16x8*)((char*)Bs + swz(4 * nc + nn, kb)) = w;
            }
        }
        __syncthreads();

#pragma unroll
        for (int s = 0; s < 2; s++) {
            bf16x8 af[4], bf[4];
#pragma unroll
            for (int i = 0; i < 4; i++)
                af[i] = *(const bf16x8*)((char*)As + swz(wm + i * 16 + lrow, 4 * s + quad));
#pragma unroll
            for (int j = 0; j < 4; j++)
                bf[j] = *(const bf16x8*)((char*)Bs + swz(wn + j * 16 + lrow, 4 * s + quad));
#pragma unroll
            for (int i = 0; i < 4; i++)
#pragma unroll
                for (int j = 0; j < 4; j++)
                    acc[i][j] = __builtin_amdgcn_mfma_f32_16x16x32_bf16(af[i], bf[j], acc[i][j], 0, 0, 0);
        }
        __syncthreads();
    }

#pragma unroll
    for (int i = 0; i < 4; i++) {
#pragma unroll
        for (int r = 0; r < 4; r++) {
            const int row = m0 + wm + i * 16 + quad * 4 + r;
            if (row < n_e) {
                const int p = list[row];
                __bf16* dst = Ybuf + (size_t)p * H_DIM + n0 + wn + lrow;
#pragma unroll
                for (int j = 0; j < 4; j++) dst[j * 16] = (__bf16)acc[i][j][r];
            }
        }
    }
}

// ---------------------------------------------------------------------------
// Kernel 4: combine.  out[t] = w[2t]*Y[2t] + w[2t+1]*Y[2t+1]  (fp32 out)
// ---------------------------------------------------------------------------
__global__ __launch_bounds__(256) void combine_kernel(
    const __bf16* __restrict__ Ybuf, const float* __restrict__ wpair,
    float* __restrict__ out)
{
    const int idx = blockIdx.x * 256 + threadIdx.x;
    const int t   = idx >> 9;
    const int hc  = (idx & 511) * 4;
    const float w0 = wpair[2 * t];
    const float w1 = wpair[2 * t + 1];
    const __bf16* y0 = Ybuf + (size_t)(2 * t) * H_DIM + hc;
    const __bf16* y1 = y0 + H_DIM;
    float4 o;
    o.x = w0 * (float)y0[0] + w1 * (float)y1[0];
    o.y = w0 * (float)y0[1] + w1 * (float)y1[1];
    o.z = w0 * (float)y0[2] + w1 * (float)y1[2];
    o.w = w0 * (float)y0[3] + w1 * (float)y1[3];
    *(float4*)(out + (size_t)t * H_DIM + hc) = o;
}

// ---------------------------------------------------------------------------
extern "C" void kernel_launch(void* const* d_in, const int* in_sizes, int n_in,
                              void* d_out, int out_size, void* d_ws, size_t ws_size,
                              hipStream_t stream)
{
    const float* hs     = (const float*)d_in[0];
    const float* gate_w = (const float*)d_in[1];
    const float* w1     = (const float*)d_in[2];
    const float* w3     = (const float*)d_in[3];
    const float* w2     = (const float*)d_in[4];
    float*       out    = (float*)d_out;

    char* ws = (char*)d_ws;
    int*    counts = (int*)(ws + 0);
    float*  wpair  = (float*)(ws + 1024);
    int*    lists  = (int*)(ws + 32768);
    __bf16* Abuf   = (__bf16*)(ws + (1 << 17));
    __bf16* Ybuf   = (__bf16*)(ws + (1 << 17) +
                               (size_t)2 * T_TOK * I_DIM * sizeof(__bf16));

    hipMemsetAsync(counts, 0, E_NUM * sizeof(int), stream);

    router_kernel<<<T_TOK, 64, 0, stream>>>(hs, gate_w, counts, lists, wpair);

    gemm1_kernel<<<dim3(I_DIM / BN, T_TOK / BM, E_NUM), 256, 0, stream>>>(
        hs, w1, w3, counts, lists, Abuf);

    gemm2_kernel<<<dim3(H_DIM / BN, T_TOK / BM, E_NUM), 256, 0, stream>>>(
        Abuf, w2, counts, lists, Ybuf);

    combine_kernel<<<(T_TOK * H_DIM / 4) / 256, 256, 0, stream>>>(Ybuf, wpair, out);
}

// Round 3
// 599.975 us; speedup vs baseline: 1.9012x; 1.2146x over previous
//
#include <hip/hip_runtime.h>
#include <hip/hip_bf16.h>

#define T_TOK 2048
#define H_DIM 2048
#define I_DIM 2048
#define E_NUM 8
#define TOPK  2

#define BM 128
#define BN 64
#define BK 64   // 8 granules of 16B (8 bf16) per LDS row

typedef float  floatx4 __attribute__((ext_vector_type(4)));
typedef __bf16 bf16x8  __attribute__((ext_vector_type(8)));
typedef __bf16 bf16x4  __attribute__((ext_vector_type(4)));

// XOR-swizzled LDS granule address (16B granules, 8 per 128-byte logical row).
// Bank position = g ^ ((row>>1)&7): 8 lanes per position (structural minimum)
// for every staging write and fragment read pattern used below.
__device__ __forceinline__ int swz(int row, int g) {
    return (row * 8 + (g ^ ((row >> 1) & 7))) * 16;
}

// ---------------------------------------------------------------------------
// Kernel 1: router — logits, top-2, renorm weights, per-expert lists,
//           PLUS fp32->bf16 conversion of hidden_states (it reads hs anyway).
// ---------------------------------------------------------------------------
__global__ __launch_bounds__(64) void router_kernel(
    const float* __restrict__ hs, const float* __restrict__ gate_w,
    int* __restrict__ counts, int* __restrict__ lists, float* __restrict__ wpair,
    __bf16* __restrict__ Xbf)
{
    const int t    = blockIdx.x;
    const int lane = threadIdx.x;

    float acc[E_NUM];
#pragma unroll
    for (int e = 0; e < E_NUM; e++) acc[e] = 0.f;

    const float4* hsrow = (const float4*)(hs + (size_t)t * H_DIM);
#pragma unroll
    for (int it = 0; it < (H_DIM / 4) / 64; it++) {
        const int c = lane + it * 64;
        const float4 x = hsrow[c];
        const bf16x4 v = {(__bf16)x.x, (__bf16)x.y, (__bf16)x.z, (__bf16)x.w};
        *(bf16x4*)(Xbf + (size_t)t * H_DIM + 4 * c) = v;
#pragma unroll
        for (int e = 0; e < E_NUM; e++) {
            const float4 w = ((const float4*)(gate_w + (size_t)e * H_DIM))[c];
            acc[e] += x.x * w.x + x.y * w.y + x.z * w.z + x.w * w.w;
        }
    }
#pragma unroll
    for (int e = 0; e < E_NUM; e++) {
        float v = acc[e];
        for (int off = 32; off >= 1; off >>= 1) v += __shfl_xor(v, off, 64);
        acc[e] = v;
    }
    if (lane == 0) {
        float l0 = -1e30f; int i0 = 0;
        for (int e = 0; e < E_NUM; e++) if (acc[e] > l0) { l0 = acc[e]; i0 = e; }
        float l1 = -1e30f; int i1 = (i0 == 0) ? 1 : 0;
        for (int e = 0; e < E_NUM; e++) if (e != i0 && acc[e] > l1) { l1 = acc[e]; i1 = e; }
        const float e1 = __expf(l1 - l0);
        const float s  = 1.f + e1;
        const int p0 = atomicAdd(&counts[i0], 1);
        lists[i0 * T_TOK + p0] = 2 * t;
        const int p1 = atomicAdd(&counts[i1], 1);
        lists[i1 * T_TOK + p1] = 2 * t + 1;
        wpair[2 * t]     = 1.f / s;
        wpair[2 * t + 1] = e1 / s;
    }
}

// ---------------------------------------------------------------------------
// Kernel 2: fused gate/up GEMM + SiLU.  A = silu(X@W1) * (X@W3), bf16 out.
// 128x64 tile, 4 waves (wave-tile 64x32), single-buffer LDS, bf16 X staging.
// ---------------------------------------------------------------------------
__global__ __launch_bounds__(256, 3) void gemm1_kernel(
    const __bf16* __restrict__ Xbf, const float* __restrict__ w1,
    const float* __restrict__ w3, const int* __restrict__ counts,
    const int* __restrict__ lists, __bf16* __restrict__ Abuf)
{
    const int e   = blockIdx.z;
    const int n_e = counts[e];
    const int m0  = blockIdx.y * BM;
    if (m0 >= n_e) return;
    const int n0 = blockIdx.x * BN;

    const int*   list = lists + e * T_TOK;
    const float* w1e  = w1 + (size_t)e * H_DIM * I_DIM;
    const float* w3e  = w3 + (size_t)e * H_DIM * I_DIM;

    __shared__ __align__(16) __bf16 Xs [BM * BK];   // 16 KB
    __shared__ __align__(16) __bf16 B1s[BN * BK];   //  8 KB
    __shared__ __align__(16) __bf16 B3s[BN * BK];   //  8 KB

    const int tid = threadIdx.x;
    // X staging: thread -> (row xr8 + 32i, granule xg). Wave covers 8 rows x 128B.
    const int xr8 = tid >> 3;        // 0..31
    const int xg  = tid & 7;         // 0..7
    // W staging: thread -> (k-granule kb, n-pair 2*np). 8 float2 -> 2 bf16x8.
    const int kb = tid >> 5;         // 0..7
    const int np = tid & 31;         // 0..31

    int tok[4];
#pragma unroll
    for (int i = 0; i < 4; i++) {
        const int r = m0 + xr8 + 32 * i;
        tok[i] = (r < n_e) ? (list[r] >> 1) : 0;
    }

    const int wave = tid >> 6;
    const int lane = tid & 63;
    const int wm   = (wave >> 1) * 64;   // 0 or 64
    const int wn   = (wave & 1) * 32;    // 0 or 32
    const int lrow = lane & 15;
    const int quad = lane >> 4;

    floatx4 accG[4][2], accU[4][2];
#pragma unroll
    for (int i = 0; i < 4; i++)
#pragma unroll
        for (int j = 0; j < 2; j++) {
            accG[i][j] = (floatx4){0.f, 0.f, 0.f, 0.f};
            accU[i][j] = (floatx4){0.f, 0.f, 0.f, 0.f};
        }

    for (int k0 = 0; k0 < H_DIM; k0 += BK) {
        // ---- stage X tile: pure bf16x8 copies (gathered rows)
#pragma unroll
        for (int i = 0; i < 4; i++) {
            const int m = xr8 + 32 * i;
            const bf16x8 v = *(const bf16x8*)(Xbf + (size_t)tok[i] * H_DIM + k0 + 8 * xg);
            *(bf16x8*)((char*)Xs + swz(m, xg)) = v;
        }
        // ---- stage W1 tile: 8 float2 loads, register transpose, 2 b128 writes
        {
            const float* src = w1e + (size_t)(k0 + 8 * kb) * I_DIM + n0 + 2 * np;
            float2 f[8];
#pragma unroll
            for (int j = 0; j < 8; j++) f[j] = *(const float2*)(src + (size_t)j * I_DIM);
            bf16x8 wlo, whi;
#pragma unroll
            for (int j = 0; j < 8; j++) { wlo[j] = (__bf16)f[j].x; whi[j] = (__bf16)f[j].y; }
            *(bf16x8*)((char*)B1s + swz(2 * np,     kb)) = wlo;
            *(bf16x8*)((char*)B1s + swz(2 * np + 1, kb)) = whi;
        }
        // ---- stage W3 tile
        {
            const float* src = w3e + (size_t)(k0 + 8 * kb) * I_DIM + n0 + 2 * np;
            float2 f[8];
#pragma unroll
            for (int j = 0; j < 8; j++) f[j] = *(const float2*)(src + (size_t)j * I_DIM);
            bf16x8 wlo, whi;
#pragma unroll
            for (int j = 0; j < 8; j++) { wlo[j] = (__bf16)f[j].x; whi[j] = (__bf16)f[j].y; }
            *(bf16x8*)((char*)B3s + swz(2 * np,     kb)) = wlo;
            *(bf16x8*)((char*)B3s + swz(2 * np + 1, kb)) = whi;
        }
        __syncthreads();

#pragma unroll
        for (int s = 0; s < 2; s++) {
            bf16x8 af[4], b1f[2], b3f[2];
#pragma unroll
            for (int i = 0; i < 4; i++)
                af[i]  = *(const bf16x8*)((char*)Xs  + swz(wm + i * 16 + lrow, 4 * s + quad));
#pragma unroll
            for (int j = 0; j < 2; j++) {
                b1f[j] = *(const bf16x8*)((char*)B1s + swz(wn + j * 16 + lrow, 4 * s + quad));
                b3f[j] = *(const bf16x8*)((char*)B3s + swz(wn + j * 16 + lrow, 4 * s + quad));
            }
#pragma unroll
            for (int i = 0; i < 4; i++)
#pragma unroll
                for (int j = 0; j < 2; j++) {
                    accG[i][j] = __builtin_amdgcn_mfma_f32_16x16x32_bf16(af[i], b1f[j], accG[i][j], 0, 0, 0);
                    accU[i][j] = __builtin_amdgcn_mfma_f32_16x16x32_bf16(af[i], b3f[j], accU[i][j], 0, 0, 0);
                }
        }
        __syncthreads();
    }

    // epilogue: silu(g)*u -> Abuf[p]  (C/D layout: col=lane&15, row=quad*4+reg)
#pragma unroll
    for (int i = 0; i < 4; i++) {
#pragma unroll
        for (int r = 0; r < 4; r++) {
            const int row = m0 + wm + i * 16 + quad * 4 + r;
            if (row < n_e) {
                const int p = list[row];
                __bf16* dst = Abuf + (size_t)p * I_DIM + n0 + wn + lrow;
#pragma unroll
                for (int j = 0; j < 2; j++) {
                    const float g = accG[i][j][r];
                    const float u = accU[i][j][r];
                    const float sv = g / (1.f + __expf(-g));
                    dst[j * 16] = (__bf16)(sv * u);
                }
            }
        }
    }
}

// ---------------------------------------------------------------------------
// Kernel 3: down-proj GEMM.  Y[p] = A[p] @ W2[e], bf16 out.  128x64 tile.
// ---------------------------------------------------------------------------
__global__ __launch_bounds__(256, 4) void gemm2_kernel(
    const __bf16* __restrict__ Abuf, const float* __restrict__ w2,
    const int* __restrict__ counts, const int* __restrict__ lists,
    __bf16* __restrict__ Ybuf)
{
    const int e   = blockIdx.z;
    const int n_e = counts[e];
    const int m0  = blockIdx.y * BM;
    if (m0 >= n_e) return;
    const int n0 = blockIdx.x * BN;

    const int*   list = lists + e * T_TOK;
    const float* w2e  = w2 + (size_t)e * I_DIM * H_DIM;

    __shared__ __align__(16) __bf16 As[BM * BK];   // 16 KB
    __shared__ __align__(16) __bf16 Bs[BN * BK];   //  8 KB

    const int tid = threadIdx.x;
    const int ar8 = tid >> 3;        // 0..31
    const int ag  = tid & 7;         // 0..7
    const int kb  = tid >> 5;        // 0..7
    const int np  = tid & 31;        // 0..31

    int prow[4];
#pragma unroll
    for (int i = 0; i < 4; i++) {
        const int r = m0 + ar8 + 32 * i;
        prow[i] = (r < n_e) ? list[r] : 0;
    }

    const int wave = tid >> 6;
    const int lane = tid & 63;
    const int wm   = (wave >> 1) * 64;
    const int wn   = (wave & 1) * 32;
    const int lrow = lane & 15;
    const int quad = lane >> 4;

    floatx4 acc[4][2];
#pragma unroll
    for (int i = 0; i < 4; i++)
#pragma unroll
        for (int j = 0; j < 2; j++) acc[i][j] = (floatx4){0.f, 0.f, 0.f, 0.f};

    for (int k0 = 0; k0 < I_DIM; k0 += BK) {
        // ---- stage A tile (bf16 gathered rows)
#pragma unroll
        for (int i = 0; i < 4; i++) {
            const int m = ar8 + 32 * i;
            const bf16x8 v = *(const bf16x8*)(Abuf + (size_t)prow[i] * I_DIM + k0 + 8 * ag);
            *(bf16x8*)((char*)As + swz(m, ag)) = v;
        }
        // ---- stage W2 tile
        {
            const float* src = w2e + (size_t)(k0 + 8 * kb) * H_DIM + n0 + 2 * np;
            float2 f[8];
#pragma unroll
            for (int j = 0; j < 8; j++) f[j] = *(const float2*)(src + (size_t)j * H_DIM);
            bf16x8 wlo, whi;
#pragma unroll
            for (int j = 0; j < 8; j++) { wlo[j] = (__bf16)f[j].x; whi[j] = (__bf16)f[j].y; }
            *(bf16x8*)((char*)Bs + swz(2 * np,     kb)) = wlo;
            *(bf16x8*)((char*)Bs + swz(2 * np + 1, kb)) = whi;
        }
        __syncthreads();

#pragma unroll
        for (int s = 0; s < 2; s++) {
            bf16x8 af[4], bf[2];
#pragma unroll
            for (int i = 0; i < 4; i++)
                af[i] = *(const bf16x8*)((char*)As + swz(wm + i * 16 + lrow, 4 * s + quad));
#pragma unroll
            for (int j = 0; j < 2; j++)
                bf[j] = *(const bf16x8*)((char*)Bs + swz(wn + j * 16 + lrow, 4 * s + quad));
#pragma unroll
            for (int i = 0; i < 4; i++)
#pragma unroll
                for (int j = 0; j < 2; j++)
                    acc[i][j] = __builtin_amdgcn_mfma_f32_16x16x32_bf16(af[i], bf[j], acc[i][j], 0, 0, 0);
        }
        __syncthreads();
    }

#pragma unroll
    for (int i = 0; i < 4; i++) {
#pragma unroll
        for (int r = 0; r < 4; r++) {
            const int row = m0 + wm + i * 16 + quad * 4 + r;
            if (row < n_e) {
                const int p = list[row];
                __bf16* dst = Ybuf + (size_t)p * H_DIM + n0 + wn + lrow;
#pragma unroll
                for (int j = 0; j < 2; j++) dst[j * 16] = (__bf16)acc[i][j][r];
            }
        }
    }
}

// ---------------------------------------------------------------------------
// Kernel 4: combine.  out[t] = w[2t]*Y[2t] + w[2t+1]*Y[2t+1]  (fp32 out)
// ---------------------------------------------------------------------------
__global__ __launch_bounds__(256) void combine_kernel(
    const __bf16* __restrict__ Ybuf, const float* __restrict__ wpair,
    float* __restrict__ out)
{
    const int idx = blockIdx.x * 256 + threadIdx.x;
    const int t   = idx >> 9;
    const int hc  = (idx & 511) * 4;
    const float w0 = wpair[2 * t];
    const float w1 = wpair[2 * t + 1];
    const __bf16* y0 = Ybuf + (size_t)(2 * t) * H_DIM + hc;
    const __bf16* y1 = y0 + H_DIM;
    float4 o;
    o.x = w0 * (float)y0[0] + w1 * (float)y1[0];
    o.y = w0 * (float)y0[1] + w1 * (float)y1[1];
    o.z = w0 * (float)y0[2] + w1 * (float)y1[2];
    o.w = w0 * (float)y0[3] + w1 * (float)y1[3];
    *(float4*)(out + (size_t)t * H_DIM + hc) = o;
}

// ---------------------------------------------------------------------------
extern "C" void kernel_launch(void* const* d_in, const int* in_sizes, int n_in,
                              void* d_out, int out_size, void* d_ws, size_t ws_size,
                              hipStream_t stream)
{
    const float* hs     = (const float*)d_in[0];
    const float* gate_w = (const float*)d_in[1];
    const float* w1     = (const float*)d_in[2];
    const float* w3     = (const float*)d_in[3];
    const float* w2     = (const float*)d_in[4];
    float*       out    = (float*)d_out;

    char* ws = (char*)d_ws;
    int*    counts = (int*)(ws + 0);
    float*  wpair  = (float*)(ws + 1024);
    int*    lists  = (int*)(ws + 32768);
    // Xbf (8 MB, live: router->gemm1) and Ybuf (16.8 MB, live: gemm2->combine)
    // share the same region — lifetimes don't overlap.
    __bf16* Xbf    = (__bf16*)(ws + (1 << 17));
    __bf16* Ybuf   = (__bf16*)(ws + (1 << 17));
    __bf16* Abuf   = (__bf16*)(ws + (1 << 17) +
                               (size_t)2 * T_TOK * H_DIM * sizeof(__bf16));

    hipMemsetAsync(counts, 0, E_NUM * sizeof(int), stream);

    router_kernel<<<T_TOK, 64, 0, stream>>>(hs, gate_w, counts, lists, wpair, Xbf);

    gemm1_kernel<<<dim3(I_DIM / BN, T_TOK / BM, E_NUM), 256, 0, stream>>>(
        Xbf, w1, w3, counts, lists, Abuf);

    gemm2_kernel<<<dim3(H_DIM / BN, T_TOK / BM, E_NUM), 256, 0, stream>>>(
        Abuf, w2, counts, lists, Ybuf);

    combine_kernel<<<(T_TOK * H_DIM / 4) / 256, 256, 0, stream>>>(Ybuf, wpair, out);
}